// Round 1
// baseline (752.370 us; speedup 1.0000x reference)
//
#include <hip/hip_runtime.h>

// ---------- lane/scalar helpers (all VALU-pipe, no DS ops) ----------

static __device__ __forceinline__ float rdlane(float v, int l) {
  return __uint_as_float(__builtin_amdgcn_readlane(__float_as_uint(v), (unsigned)l));
}

template <int CTRL>
static __device__ __forceinline__ float qperm(float v) {
  // DPP quad_perm: pure VALU cross-lane within each 4-lane quad.
  return __uint_as_float(__builtin_amdgcn_update_dpp(
      0u, __float_as_uint(v), CTRL, 0xF, 0xF, true));
}

static __device__ __forceinline__ float exp2a(float x) {
  float r;
  asm("v_exp_f32 %0, %1" : "=v"(r) : "v"(x));
  return r;
}
static __device__ __forceinline__ float rcpa(float x) {
  return __builtin_amdgcn_rcpf(x);
}

// act = A * rcp(1 + exp2(B*x)) + C  — sigmoid (A=1,B=-log2e,C=0) or
// tanh (A=2,B=-2log2e,C=-1) selected by per-lane constants -> no divergence.
static __device__ __forceinline__ float act_unified(float x, float A, float B, float C) {
  return __fmaf_rn(A, rcpa(1.f + exp2a(B * x)), C);
}
static __device__ __forceinline__ float tanh_fast(float x) {
  return __fmaf_rn(2.f, rcpa(1.f + exp2a(-2.8853900817779268f * x)), -1.f);
}

#define QP_XOR1 0xB1  // [1,0,3,2]
#define QP_XOR2 0x4E  // [2,3,0,1]
#define QP_XOR3 0x1B  // [3,2,1,0]
#define QP_BC0  0x00  // [0,0,0,0] broadcast quad-base

// One wave64 per batch element. lane = 4*j + gt  (j: hidden unit 0..15,
// gt: gate 0..3 in torch order i,f,g,o; torch row = gt*16 + j).
__global__ __launch_bounds__(64, 1) void vdd_lstm_kernel(
    const float* __restrict__ x,      // [B,T]
    const float* __restrict__ Wih1,   // [64]
    const float* __restrict__ Whh1,   // [64,16]
    const float* __restrict__ b1,     // [64]
    const float* __restrict__ Wih2,   // [4,16]
    const float* __restrict__ Whh2,   // [4]
    const float* __restrict__ b2,     // [4]
    const float* __restrict__ mask1,  // [B,16]
    const float* __restrict__ mask2,  // [B]
    float* __restrict__ out,          // [B,T]
    int T) {
  const int b = blockIdx.x;
  const int lane = threadIdx.x;  // block = 64 threads
  const int j = lane >> 2;
  const int gt = lane & 3;
  const int row = gt * 16 + j;

  // Per-lane weights. mask1 is folded into layer-2 input weights:
  // sum_k Wih2[gt][k] * (h[k]*m1[k])  ==  sum_k (Wih2[gt][k]*m1[k]) * h[k]
  float w[16], w2m[16];
#pragma unroll
  for (int k = 0; k < 16; ++k) w[k] = Whh1[row * 16 + k];
#pragma unroll
  for (int k = 0; k < 16; ++k) w2m[k] = Wih2[gt * 16 + k] * mask1[b * 16 + k];

  const float wih1 = Wih1[row];
  const float bb1  = b1[row];
  const float whh2 = Whh2[gt];
  const float bb2  = b2[gt];
  const float m2   = mask2[b];

  const bool isg = (gt == 2);                                 // tanh gate
  const float aA = isg ? 2.f : 1.f;
  const float aB = isg ? -2.8853900817779268f : -1.4426950408889634f;
  const float aC = isg ? -1.f : 0.f;

  const float* xb = x + (size_t)b * T;
  float* ob = out + (size_t)b * T;

  float h = 0.f, c = 0.f;     // layer-1 state (valid on quad-base lanes)
  float c2 = 0.f, h2b = 0.f;  // layer-2 state (h2b broadcast to all lanes)

  float xcur = xb[lane];      // x chunk [0,64)
  const int NCH = T >> 6;     // T is a multiple of 64 (4096)

  for (int ch = 0; ch < NCH; ++ch) {
    // Prefetch next x chunk (coalesced); dummy-safe for the last chunk.
    int nb = (ch + 1) << 6;
    nb = (nb + 64 <= T) ? nb : 0;
    float xnext = xb[nb + lane];

    float och = 0.f;  // out chunk: lane L holds out[ch*64 + L]

#pragma unroll 4
    for (int s = 0; s < 64; ++s) {
      // ---- broadcast h(t-1) into SGPRs (quad-base lanes hold h[j])
      float sh[16];
#pragma unroll
      for (int k = 0; k < 16; ++k) sh[k] = rdlane(h, 4 * k);
      float sx = rdlane(xcur, s);  // x_t, SGPR lane index (wave-uniform)

      // ---- layer-1 gate pre-activation: Wih1*x + b1 + Whh1[row,:] . h
      float p0 = __fmaf_rn(wih1, sx, bb1);
      p0 = __fmaf_rn(w[0], sh[0], p0);
      float p1 = w[1] * sh[1];
      float p2 = w[2] * sh[2];
      float p3 = w[3] * sh[3];
#pragma unroll
      for (int k = 4; k < 16; k += 4) {
        p0 = __fmaf_rn(w[k + 0], sh[k + 0], p0);
        p1 = __fmaf_rn(w[k + 1], sh[k + 1], p1);
        p2 = __fmaf_rn(w[k + 2], sh[k + 2], p2);
        p3 = __fmaf_rn(w[k + 3], sh[k + 3], p3);
      }
      float pre = (p0 + p1) + (p2 + p3);

      // ---- activation (per-lane unified) + quad gather + state update
      float a1 = act_unified(pre, aA, aB, aC);
      float fg = qperm<QP_XOR1>(a1);   // f at quad-base
      float gg = qperm<QP_XOR2>(a1);   // g at quad-base
      float og = qperm<QP_XOR3>(a1);   // o at quad-base
      c = __fmaf_rn(fg, c, a1 * gg);   // valid on quad-base lanes (a1 = i there)
      h = og * tanh_fast(c);           // valid on quad-base lanes

      // ---- broadcast h(t) for layer 2
      float sh2[16];
#pragma unroll
      for (int k = 0; k < 16; ++k) sh2[k] = rdlane(h, 4 * k);

      // ---- layer-2: red = b2 + (Wih2*m1) . h(t)    (all-VALU, replicated)
      float q0 = __fmaf_rn(w2m[0], sh2[0], bb2);
      float q1 = w2m[1] * sh2[1];
      float q2 = w2m[2] * sh2[2];
      float q3 = w2m[3] * sh2[3];
#pragma unroll
      for (int k = 4; k < 16; k += 4) {
        q0 = __fmaf_rn(w2m[k + 0], sh2[k + 0], q0);
        q1 = __fmaf_rn(w2m[k + 1], sh2[k + 1], q1);
        q2 = __fmaf_rn(w2m[k + 2], sh2[k + 2], q2);
        q3 = __fmaf_rn(w2m[k + 3], sh2[k + 3], q3);
      }
      float red = (q0 + q1) + (q2 + q3);

      float pre2 = __fmaf_rn(whh2, h2b, red);
      float a2 = act_unified(pre2, aA, aB, aC);
      float f2 = qperm<QP_XOR1>(a2);
      float g2 = qperm<QP_XOR2>(a2);
      float o2 = qperm<QP_XOR3>(a2);
      c2 = __fmaf_rn(f2, c2, a2 * g2);       // valid on quad-base lanes
      float h2l = o2 * tanh_fast(c2);        // valid on quad-base lanes
      h2b = qperm<QP_BC0>(h2l);              // broadcast to all lanes

      // ---- output select into chunk register (slot s)
      float ov = h2b * m2;
      och = (lane == s) ? ov : och;
    }

    ob[(ch << 6) + lane] = och;  // coalesced 256B store per wave
    xcur = xnext;
  }
}

extern "C" void kernel_launch(void* const* d_in, const int* in_sizes, int n_in,
                              void* d_out, int out_size, void* d_ws, size_t ws_size,
                              hipStream_t stream) {
  const float* x     = (const float*)d_in[0];
  const float* Wih1  = (const float*)d_in[1];
  const float* Whh1  = (const float*)d_in[2];
  const float* b1    = (const float*)d_in[3];
  const float* Wih2  = (const float*)d_in[4];
  const float* Whh2  = (const float*)d_in[5];
  const float* b2    = (const float*)d_in[6];
  const float* mask1 = (const float*)d_in[7];
  const float* mask2 = (const float*)d_in[8];
  float* out = (float*)d_out;

  const int B = in_sizes[8];           // mask2 has B elements
  const int T = in_sizes[0] / B;       // x is [B,T,1]

  vdd_lstm_kernel<<<dim3(B), dim3(64), 0, stream>>>(
      x, Wih1, Whh1, b1, Wih2, Whh2, b2, mask1, mask2, out, T);
}

// Round 3
// 670.622 us; speedup vs baseline: 1.1219x; 1.1219x over previous
//
#include <hip/hip_runtime.h>

// ---------- lane/scalar helpers (all VALU-pipe, no DS ops) ----------

static __device__ __forceinline__ float rdlane(float v, int l) {
  return __uint_as_float(__builtin_amdgcn_readlane(__float_as_uint(v), (unsigned)l));
}

template <int CTRL>
static __device__ __forceinline__ float qperm(float v) {
  // DPP quad_perm: pure VALU cross-lane within each 4-lane quad.
  return __uint_as_float(__builtin_amdgcn_update_dpp(
      0u, __float_as_uint(v), CTRL, 0xF, 0xF, true));
}

template <int N>
static __device__ __forceinline__ float rowror(float v) {
  // DPP row rotate (within each 16-lane row) — VALU pipe.
  return __uint_as_float(__builtin_amdgcn_update_dpp(
      0u, __float_as_uint(v), 0x120 | N, 0xF, 0xF, true));
}

// Cross-row exchange+add via gfx950 permlane swaps (VALU pipe, no DS).
// HARDENED: explicit v_mov into an early-clobber register guarantees the two
// operands are DISTINCT physical registers (the previous "+v"(a),"+v"(b) with
// a==b==v let the allocator coalesce both into one reg -> self-swap -> wrong
// sums). s_nop 1 covers the VALU-write -> permlane-read wait-state hazard.
static __device__ __forceinline__ float xswapadd16(float v) {
  float a = v, b;
  asm("v_mov_b32 %0, %1\n\t"
      "s_nop 1\n\t"
      "v_permlane16_swap_b32 %1, %0"
      : "=&v"(b), "+v"(a));
  return a + b;  // rows {0,1} get r0+r1; rows {2,3} get r2+r3 (per 32-half)
}
static __device__ __forceinline__ float xswapadd32(float v) {
  float a = v, b;
  asm("v_mov_b32 %0, %1\n\t"
      "s_nop 1\n\t"
      "v_permlane32_swap_b32 %1, %0"
      : "=&v"(b), "+v"(a));
  return a + b;  // all lanes get lo32 + hi32
}

static __device__ __forceinline__ float exp2a(float x) {
  float r;
  asm("v_exp_f32 %0, %1" : "=v"(r) : "v"(x));
  return r;
}
static __device__ __forceinline__ float rcpa(float x) {
  return __builtin_amdgcn_rcpf(x);
}

#define QP_BC0 0x00  // [0,0,0,0] broadcast quad lane 0 (i)
#define QP_BC1 0x55  // [1,1,1,1] broadcast quad lane 1 (f)
#define QP_BC2 0xAA  // [2,2,2,2] broadcast quad lane 2 (g)
#define QP_BC3 0xFF  // [3,3,3,3] broadcast quad lane 3 (o)

// One wave64 per batch element. lane = 4*j + gt  (j: hidden unit 0..15,
// gt: gate 0..3 in torch order i,f,g,o; torch row = gt*16 + j).
//
// All activation input scales are folded into the weights:
//   sigmoid gates: weights *= -log2e   -> a = rcp(1+exp2(pre))
//   g (tanh) gate: weights *= -2log2e  -> raw = rcp(1+exp2(pre)),
//     and the gate value is produced PRE-SCALED by -2log2e
//     (aA=-4log2e, aC=+2log2e) so the cell state is cs = -2log2e * c.
//   Then tanh(c) = 2*rcp(1+exp2(cs)) - 1 with no input multiply.
__global__ __launch_bounds__(64, 1) void vdd_lstm_kernel(
    const float* __restrict__ x,      // [B,T]
    const float* __restrict__ Wih1,   // [64]
    const float* __restrict__ Whh1,   // [64,16]
    const float* __restrict__ b1,     // [64]
    const float* __restrict__ Wih2,   // [4,16]
    const float* __restrict__ Whh2,   // [4]
    const float* __restrict__ b2,     // [4]
    const float* __restrict__ mask1,  // [B,16]
    const float* __restrict__ mask2,  // [B]
    float* __restrict__ out,          // [B,T]
    int T) {
  const int b = blockIdx.x;
  const int lane = threadIdx.x;  // block = 64 threads
  const int j = lane >> 2;
  const int gt = lane & 3;
  const int row = gt * 16 + j;

  const float LOG2E = 1.4426950408889634f;
  const bool isg = (gt == 2);
  const float sc = isg ? (-2.f * LOG2E) : (-LOG2E);  // pre-activation scale
  const float aA = isg ? (-4.f * LOG2E) : 1.f;       // output scale (g pre-scaled)
  const float aC = isg ? (2.f * LOG2E) : 0.f;

  // Per-lane weights, pre-scaled.
  float w[16];
#pragma unroll
  for (int k = 0; k < 16; ++k) w[k] = Whh1[row * 16 + k] * sc;
  const float wih1 = Wih1[row] * sc;
  const float bb1  = b1[row] * sc;
  // Layer-2: ONE weight per lane (unit j, gate gt), mask1 + scale folded.
  const float w2l  = Wih2[gt * 16 + j] * mask1[b * 16 + j] * sc;
  const float whh2 = Whh2[gt] * sc;
  const float bb2  = b2[gt] * sc;
  const float m2   = mask2[b];
  const float two_m2 = 2.f * m2, neg_m2 = -m2;  // mask2 folded into tanh fma

  const float* xb = x + (size_t)b * T;
  float* ob = out + (size_t)b * T;

  float h = 0.f, cs = 0.f;    // layer-1 state (valid on ALL lanes)
  float cs2 = 0.f, h2b = 0.f; // layer-2 state (valid on ALL lanes)

  float xcur = xb[lane];      // x chunk [0,64)
  const int NCH = T >> 6;     // T multiple of 64

  for (int ch = 0; ch < NCH; ++ch) {
    int nb = (ch + 1) << 6;
    nb = (nb + 64 <= T) ? nb : 0;
    float xnext = xb[nb + lane];  // coalesced prefetch

    float och = 0.f;  // out chunk: lane L holds out[ch*64 + L]

#pragma unroll 8
    for (int s = 0; s < 64; ++s) {
      // ---- broadcast h(t-1) into SGPRs (any lane of quad k holds h[k])
      float sh[16];
#pragma unroll
      for (int k = 0; k < 16; ++k) sh[k] = rdlane(h, 4 * k);
      float sx = rdlane(xcur, s);  // x_t (wave-uniform)

      // Layer-2 early part (off the critical chain): whh2*h2(t-1) + b2
      float pre2b = __fmaf_rn(whh2, h2b, bb2);

      // ---- layer-1 pre-activation (pre-scaled): Wih1*x + b1 + Whh1 . h
      float p0 = __fmaf_rn(wih1, sx, bb1);
      p0 = __fmaf_rn(w[0], sh[0], p0);
      float p1 = w[1] * sh[1];
      float p2 = w[2] * sh[2];
      float p3 = w[3] * sh[3];
#pragma unroll
      for (int k = 4; k < 16; k += 4) {
        p0 = __fmaf_rn(w[k + 0], sh[k + 0], p0);
        p1 = __fmaf_rn(w[k + 1], sh[k + 1], p1);
        p2 = __fmaf_rn(w[k + 2], sh[k + 2], p2);
        p3 = __fmaf_rn(w[k + 3], sh[k + 3], p3);
      }
      float pre = (p0 + p1) + (p2 + p3);

      // ---- layer-1 activation + quad broadcast + state update (ALL lanes)
      float a1 = __fmaf_rn(aA, rcpa(1.f + exp2a(pre)), aC);
      float i1 = qperm<QP_BC0>(a1);
      float f1 = qperm<QP_BC1>(a1);
      float g1 = qperm<QP_BC2>(a1);  // pre-scaled by -2log2e
      float o1 = qperm<QP_BC3>(a1);
      cs = __fmaf_rn(f1, cs, i1 * g1);                    // cs = -2log2e * c
      float th = __fmaf_rn(2.f, rcpa(1.f + exp2a(cs)), -1.f);
      h = o1 * th;                                        // h(t), all lanes

      // ---- layer-2 dot via in-wave reduction (stride-4 gt-preserving):
      // lane 4j+gt: product h[j] * (Wih2[gt,j]*m1[j]*sc); reduce over j.
      float v2 = h * w2l;
      float r = v2 + rowror<4>(v2);
      r = r + rowror<8>(r);          // within-row (4 same-gt lanes) sum
      r = xswapadd16(r);             // + partner row of 16
      r = xswapadd32(r);             // + other 32-half -> full sum, all lanes
      float pre2 = pre2b + r;

      // ---- layer-2 activation + update (ALL lanes; same gt layout)
      float a2 = __fmaf_rn(aA, rcpa(1.f + exp2a(pre2)), aC);
      float i2 = qperm<QP_BC0>(a2);
      float f2 = qperm<QP_BC1>(a2);
      float g2 = qperm<QP_BC2>(a2);
      float o2 = qperm<QP_BC3>(a2);
      cs2 = __fmaf_rn(f2, cs2, i2 * g2);
      float th2m = __fmaf_rn(two_m2, rcpa(1.f + exp2a(cs2)), neg_m2);
      h2b = o2 * __fmaf_rn(2.f, rcpa(1.f + exp2a(cs2)), -1.f);
      float ov = o2 * th2m;          // h2 * mask2

      och = (lane == s) ? ov : och;
    }

    ob[(ch << 6) + lane] = och;  // coalesced 256B store per wave
    xcur = xnext;
  }
}

extern "C" void kernel_launch(void* const* d_in, const int* in_sizes, int n_in,
                              void* d_out, int out_size, void* d_ws, size_t ws_size,
                              hipStream_t stream) {
  const float* x     = (const float*)d_in[0];
  const float* Wih1  = (const float*)d_in[1];
  const float* Whh1  = (const float*)d_in[2];
  const float* b1    = (const float*)d_in[3];
  const float* Wih2  = (const float*)d_in[4];
  const float* Whh2  = (const float*)d_in[5];
  const float* b2    = (const float*)d_in[6];
  const float* mask1 = (const float*)d_in[7];
  const float* mask2 = (const float*)d_in[8];
  float* out = (float*)d_out;

  const int B = in_sizes[8];      // mask2 has B elements
  const int T = in_sizes[0] / B;  // x is [B,T,1]

  vdd_lstm_kernel<<<dim3(B), dim3(64), 0, stream>>>(
      x, Wih1, Whh1, b1, Wih2, Whh2, b2, mask1, mask2, out, T);
}

// Round 4
// 644.735 us; speedup vs baseline: 1.1669x; 1.0402x over previous
//
#include <hip/hip_runtime.h>

// ---------- lane/scalar helpers (all VALU-pipe, no DS ops) ----------

static __device__ __forceinline__ float rdlane(float v, int l) {
  return __uint_as_float(__builtin_amdgcn_readlane(__float_as_uint(v), (unsigned)l));
}

template <int CTRL>
static __device__ __forceinline__ float qperm(float v) {
  // DPP quad_perm: pure VALU cross-lane within each 4-lane quad.
  return __uint_as_float(__builtin_amdgcn_update_dpp(
      0u, __float_as_uint(v), CTRL, 0xF, 0xF, true));
}

template <int N>
static __device__ __forceinline__ float rowror(float v) {
  // DPP row rotate (within each 16-lane row) — VALU pipe.
  return __uint_as_float(__builtin_amdgcn_update_dpp(
      0u, __float_as_uint(v), 0x120 | N, 0xF, 0xF, true));
}

// Cross-row exchange+add via gfx950 permlane swaps (VALU pipe, no DS).
// Explicit v_mov into an early-clobber register guarantees DISTINCT physical
// registers (tied "+v"/"+v" on one SSA value coalesces -> self-swap bug).
// s_nop 1 covers the VALU-write -> permlane-read wait-state hazard.
static __device__ __forceinline__ float xswapadd16(float v) {
  float a = v, b;
  asm("v_mov_b32 %0, %1\n\t"
      "s_nop 1\n\t"
      "v_permlane16_swap_b32 %1, %0"
      : "=&v"(b), "+v"(a));
  return a + b;  // rows {0,1} get r0+r1; rows {2,3} get r2+r3 (per 32-half)
}
static __device__ __forceinline__ float xswapadd32(float v) {
  float a = v, b;
  asm("v_mov_b32 %0, %1\n\t"
      "s_nop 1\n\t"
      "v_permlane32_swap_b32 %1, %0"
      : "=&v"(b), "+v"(a));
  return a + b;  // all lanes get lo32 + hi32
}

static __device__ __forceinline__ float exp2a(float x) {
  float r;
  asm("v_exp_f32 %0, %1" : "=v"(r) : "v"(x));
  return r;
}
static __device__ __forceinline__ float rcpa(float x) {
  return __builtin_amdgcn_rcpf(x);
}

#define QP_BC0 0x00  // broadcast quad lane 0 (i)
#define QP_BC1 0x55  // broadcast quad lane 1 (f)
#define QP_BC2 0xAA  // broadcast quad lane 2 (g)
#define QP_BC3 0xFF  // broadcast quad lane 3 (o)

// One wave64 per batch element. lane = 4*j + gt  (j: hidden unit 0..15,
// gt: gate 0..3 in torch order i,f,g,o; torch row = gt*16 + j).
//
// Scale folding (as in R3): sigmoid rows *= -log2e, g rows *= -2log2e,
// g-gate output pre-scaled by -2log2e so cs = -2log2e*c and
// tanh(c) = 2*rcp(1+exp2(cs)) - 1 with no input multiply.
//
// SOFTWARE PIPELINE (new): body (ch,s) computes layer-2 for step g=ch*64+s
// (consuming h=h1(g)) AND layer-1 for step g+1 (also consuming h1(g)).
// The two ~130-cyc dependency chains are independent -> scheduler overlaps.
__global__ __launch_bounds__(64, 1) void vdd_lstm_kernel(
    const float* __restrict__ x,      // [B,T]
    const float* __restrict__ Wih1,   // [64]
    const float* __restrict__ Whh1,   // [64,16]
    const float* __restrict__ b1,     // [64]
    const float* __restrict__ Wih2,   // [4,16]
    const float* __restrict__ Whh2,   // [4]
    const float* __restrict__ b2,     // [4]
    const float* __restrict__ mask1,  // [B,16]
    const float* __restrict__ mask2,  // [B]
    float* __restrict__ out,          // [B,T]
    int T) {
  const int b = blockIdx.x;
  const int lane = threadIdx.x;  // block = 64 threads
  const int j = lane >> 2;
  const int gt = lane & 3;
  const int row = gt * 16 + j;

  const float LOG2E = 1.4426950408889634f;
  const bool isg = (gt == 2);
  const float sc = isg ? (-2.f * LOG2E) : (-LOG2E);
  const float aA = isg ? (-4.f * LOG2E) : 1.f;
  const float aC = isg ? (2.f * LOG2E) : 0.f;

  float w[16];
#pragma unroll
  for (int k = 0; k < 16; ++k) w[k] = Whh1[row * 16 + k] * sc;
  const float wih1 = Wih1[row] * sc;
  const float bb1  = b1[row] * sc;
  const float w2l  = Wih2[gt * 16 + j] * mask1[b * 16 + j] * sc;
  const float whh2 = Whh2[gt] * sc;
  const float bb2  = b2[gt] * sc;
  const float m2   = mask2[b];

  const float* xb = x + (size_t)b * T;
  float* ob = out + (size_t)b * T;

  float h = 0.f, cs = 0.f;     // layer-1 state (all lanes)
  float cs2 = 0.f, h2b = 0.f;  // layer-2 state (all lanes)

  float xcur = xb[lane];       // x chunk [0,64)
  const int NCH = T >> 6;

  // ---- prologue: layer-1 for step 0 (h_prev = 0 -> no Whh1 term) ----
  {
    float sx = rdlane(xcur, 0);
    float pre = __fmaf_rn(wih1, sx, bb1);
    float a1 = __fmaf_rn(aA, rcpa(1.f + exp2a(pre)), aC);
    float i1 = qperm<QP_BC0>(a1);
    float g1 = qperm<QP_BC2>(a1);
    float o1 = qperm<QP_BC3>(a1);
    cs = i1 * g1;  // f*0 + i*g
    h = o1 * __fmaf_rn(2.f, rcpa(1.f + exp2a(cs)), -1.f);
  }

  for (int ch = 0; ch < NCH; ++ch) {
    int nb = (ch + 1) << 6;
    nb = (nb + 64 <= T) ? nb : 0;
    float xnext = xb[nb + lane];  // coalesced prefetch (dummy for last chunk)

    float och = 0.f;  // out chunk: lane L holds out[ch*64 + L]

#pragma unroll 8
    for (int s = 0; s < 64; ++s) {
      // ---- x for layer-1 of step g+1 (one ahead; crosses chunk at s=63)
      float xsrc = (s < 63) ? xcur : xnext;
      float sx = rdlane(xsrc, (s + 1) & 63);

      // ---- both chains start from h = h1(g) ----
      // layer-1 (step g+1): broadcast h into SGPRs
      float sh[16];
#pragma unroll
      for (int k = 0; k < 16; ++k) sh[k] = rdlane(h, 4 * k);

      // layer-2 (step g): per-lane product, in-wave stride-4 reduction
      float v2 = h * w2l;

      // layer-1 pre-activation (pre-scaled)
      float p0 = __fmaf_rn(wih1, sx, bb1);
      p0 = __fmaf_rn(w[0], sh[0], p0);
      float p1 = w[1] * sh[1];
      float p2 = w[2] * sh[2];
      float p3 = w[3] * sh[3];
#pragma unroll
      for (int k = 4; k < 16; k += 4) {
        p0 = __fmaf_rn(w[k + 0], sh[k + 0], p0);
        p1 = __fmaf_rn(w[k + 1], sh[k + 1], p1);
        p2 = __fmaf_rn(w[k + 2], sh[k + 2], p2);
        p3 = __fmaf_rn(w[k + 3], sh[k + 3], p3);
      }
      float pre = (p0 + p1) + (p2 + p3);

      // layer-2 reduction (independent of layer-1 chain)
      float r = v2 + rowror<4>(v2);
      r = r + rowror<8>(r);
      r = xswapadd16(r);
      r = xswapadd32(r);
      float pre2 = __fmaf_rn(whh2, h2b, bb2) + r;

      // layer-1 activation + state update -> h_new
      float a1 = __fmaf_rn(aA, rcpa(1.f + exp2a(pre)), aC);
      float i1 = qperm<QP_BC0>(a1);
      float f1 = qperm<QP_BC1>(a1);
      float g1 = qperm<QP_BC2>(a1);
      float o1 = qperm<QP_BC3>(a1);
      cs = __fmaf_rn(f1, cs, i1 * g1);
      float hn = o1 * __fmaf_rn(2.f, rcpa(1.f + exp2a(cs)), -1.f);

      // layer-2 activation + state update -> ov (wave-uniform)
      float a2 = __fmaf_rn(aA, rcpa(1.f + exp2a(pre2)), aC);
      float i2 = qperm<QP_BC0>(a2);
      float f2 = qperm<QP_BC1>(a2);
      float g2 = qperm<QP_BC2>(a2);
      float o2 = qperm<QP_BC3>(a2);
      cs2 = __fmaf_rn(f2, cs2, i2 * g2);
      h2b = o2 * __fmaf_rn(2.f, rcpa(1.f + exp2a(cs2)), -1.f);
      float ov = h2b * m2;

      och = (lane == s) ? ov : och;
      h = hn;
    }

    ob[(ch << 6) + lane] = och;  // coalesced store
    xcur = xnext;
  }
}

extern "C" void kernel_launch(void* const* d_in, const int* in_sizes, int n_in,
                              void* d_out, int out_size, void* d_ws, size_t ws_size,
                              hipStream_t stream) {
  const float* x     = (const float*)d_in[0];
  const float* Wih1  = (const float*)d_in[1];
  const float* Whh1  = (const float*)d_in[2];
  const float* b1    = (const float*)d_in[3];
  const float* Wih2  = (const float*)d_in[4];
  const float* Whh2  = (const float*)d_in[5];
  const float* b2    = (const float*)d_in[6];
  const float* mask1 = (const float*)d_in[7];
  const float* mask2 = (const float*)d_in[8];
  float* out = (float*)d_out;

  const int B = in_sizes[8];      // mask2 has B elements
  const int T = in_sizes[0] / B;  // x is [B,T,1]

  vdd_lstm_kernel<<<dim3(B), dim3(64), 0, stream>>>(
      x, Wih1, Whh1, b1, Wih2, Whh2, b2, mask1, mask2, out, T);
}